// Round 7
// baseline (592.263 us; speedup 1.0000x reference)
//
#include <hip/hip_runtime.h>
#include <math.h>

#define D_MODEL 1024
#define N_SEQ   4096
#define N_HEADS 16
#define DHEAD   64
#define QKV_COLS 3072   // 3 * 1024

typedef short bf16x8 __attribute__((ext_vector_type(8)));
typedef short bf16x4 __attribute__((ext_vector_type(4)));
typedef float f32x4  __attribute__((ext_vector_type(4)));

#define MFMA32(a, b, c) __builtin_amdgcn_mfma_f32_16x16x32_bf16(a, b, c, 0, 0, 0)
#define MFMA16(a, b, c) __builtin_amdgcn_mfma_f32_16x16x16bf16_1k(a, b, c, 0, 0, 0)

#define QSCALE  0.18033688011112042f   // 0.125 * log2(e), folded into q
#define NLOG2TH 0.41524101186092029f   // log2(10000)/32; inv_freq_i = 2^(-i*NLOG2TH)

static __device__ __forceinline__ unsigned short f2bf(float f) {
    union { float f; unsigned u; } v; v.f = f;
    unsigned r = (v.u + 0x7fffu + ((v.u >> 16) & 1u)) >> 16;
    return (unsigned short)r;
}
static __device__ __forceinline__ float bf2f(unsigned short u) {
    union { unsigned u; float f; } v; v.u = ((unsigned)u) << 16; return v.f;
}
// pack 2 floats -> u32 of 2 bf16 (truncating) via one v_perm
static __device__ __forceinline__ unsigned packbf2(float a, float b) {
    union { float f; unsigned u; } x0, x1; x0.f = a; x1.f = b;
    return __builtin_amdgcn_perm(x1.u, x0.u, 0x07060302u);
}
static __device__ __forceinline__ bf16x4 pack_bf16x4(float a, float b, float c, float d) {
    union { unsigned u[2]; bf16x4 v; } r;
    r.u[0] = packbf2(a, b);
    r.u[1] = packbf2(c, d);
    return r.v;
}

typedef __attribute__((address_space(1))) const void* gas_t;
typedef __attribute__((address_space(3))) void* las_t;
static __device__ __forceinline__ void load_lds16(const unsigned short* g, unsigned short* l) {
    __builtin_amdgcn_global_load_lds((gas_t)g, (las_t)l, 16, 0, 0);
}

// ---------------- LayerNorm: one block per row, bf16 out ----------------
__global__ __launch_bounds__(256) void ln_kernel(const float* __restrict__ x,
                                                 const float* __restrict__ g,
                                                 const float* __restrict__ b,
                                                 unsigned short* __restrict__ h) {
    int row = blockIdx.x;
    int t = threadIdx.x;
    float4 v = ((const float4*)(x + (size_t)row * D_MODEL))[t];
    float s  = v.x + v.y + v.z + v.w;
    float ss = v.x*v.x + v.y*v.y + v.z*v.z + v.w*v.w;
    for (int off = 32; off; off >>= 1) {
        s  += __shfl_down(s, off);
        ss += __shfl_down(ss, off);
    }
    __shared__ float sm[4], ssm[4];
    __shared__ float mu_s, rs_s;
    int wave = t >> 6, lane = t & 63;
    if (lane == 0) { sm[wave] = s; ssm[wave] = ss; }
    __syncthreads();
    if (t == 0) {
        float S = 0.f, SS = 0.f;
        for (int w = 0; w < 4; w++) { S += sm[w]; SS += ssm[w]; }
        float mu = S / D_MODEL;
        float var = SS / D_MODEL - mu * mu;
        mu_s = mu;
        rs_s = rsqrtf(var + 1e-5f);
    }
    __syncthreads();
    float mu = mu_s, rs = rs_s;
    float4 gv = ((const float4*)g)[t];
    float4 bv = ((const float4*)b)[t];
    ushort4 o;
    o.x = f2bf((v.x - mu) * rs * gv.x + bv.x);
    o.y = f2bf((v.y - mu) * rs * gv.y + bv.y);
    o.z = f2bf((v.z - mu) * rs * gv.z + bv.z);
    o.w = f2bf((v.w - mu) * rs * gv.w + bv.w);
    *(ushort4*)(h + (size_t)row * D_MODEL + t * 4) = o;
}

// ------------- transpose + fp32->bf16: W[K][N] -> Wt[N][K] -------------
__global__ __launch_bounds__(256) void transpose_cvt(const float* __restrict__ W,
                                                     unsigned short* __restrict__ Wt,
                                                     int K, int N) {
    __shared__ float tile[64][65];
    int k0 = blockIdx.x * 64, n0 = blockIdx.y * 64;
    int t = threadIdx.x;
#pragma unroll
    for (int p = 0; p < 16; p++) {
        int idx = p * 256 + t;
        int r = idx >> 6, c = idx & 63;
        tile[r][c] = W[(size_t)(k0 + r) * N + n0 + c];
    }
    __syncthreads();
#pragma unroll
    for (int p = 0; p < 16; p++) {
        int idx = p * 256 + t;
        int r2 = idx >> 6, c2 = idx & 63;
        Wt[(size_t)(n0 + r2) * K + k0 + c2] = f2bf(tile[c2][r2]);
    }
}

// ---- generic MFMA bf16 GEMM (for out-proj): C = A * Bt^T, fp32 out ----
__global__ __launch_bounds__(256) void gemm_bt128(const unsigned short* __restrict__ A,
                                                  const unsigned short* __restrict__ Bt,
                                                  float* __restrict__ C,
                                                  int M, int N, int K) {
    __shared__ unsigned short As[128 * 32];
    __shared__ unsigned short Bs[128 * 32];
    int t = threadIdx.x;
    int w = t >> 6, lane = t & 63;
    int l16 = lane & 15, quad = lane >> 4;
    int wr = w >> 1, wc = w & 1;
    int m0 = blockIdx.x * 128, n0 = blockIdx.y * 128;
    int srow = lane >> 2, scol = (lane & 3) * 8;
    int c0 = w * 2, c1 = c0 + 1;

    f32x4 acc[4][4] = {};

    for (int k0 = 0; k0 < K; k0 += 32) {
        __syncthreads();
        load_lds16(A  + (size_t)(m0 + c0 * 16 + srow) * K + k0 + scol, &As[c0 * 512 + lane * 8]);
        load_lds16(A  + (size_t)(m0 + c1 * 16 + srow) * K + k0 + scol, &As[c1 * 512 + lane * 8]);
        load_lds16(Bt + (size_t)(n0 + c0 * 16 + srow) * K + k0 + scol, &Bs[c0 * 512 + lane * 8]);
        load_lds16(Bt + (size_t)(n0 + c1 * 16 + srow) * K + k0 + scol, &Bs[c1 * 512 + lane * 8]);
        __syncthreads();
        bf16x8 a[4], b[4];
#pragma unroll
        for (int mt = 0; mt < 4; mt++)
            a[mt] = *(const bf16x8*)&As[(wr * 64 + mt * 16 + l16) * 32 + quad * 8];
#pragma unroll
        for (int nt = 0; nt < 4; nt++)
            b[nt] = *(const bf16x8*)&Bs[(wc * 64 + nt * 16 + l16) * 32 + quad * 8];
#pragma unroll
        for (int mt = 0; mt < 4; mt++)
#pragma unroll
            for (int nt = 0; nt < 4; nt++)
                acc[mt][nt] = MFMA32(a[mt], b[nt], acc[mt][nt]);
    }
#pragma unroll
    for (int mt = 0; mt < 4; mt++)
#pragma unroll
        for (int nt = 0; nt < 4; nt++)
#pragma unroll
            for (int r = 0; r < 4; r++)
                C[(size_t)(m0 + wr * 64 + mt * 16 + quad * 4 + r) * N + n0 + wc * 64 + nt * 16 + l16] =
                    acc[mt][nt][r];
}

// ---- fused QKV GEMM: epilogue writes caches + rope'd k + scaled q + v^T ----
// by 0..7: q-block -> q_bf (scaled, unroped). by 8..15: k-block -> out_k fp32 +
// roped k_bf. by 16..23: v-block -> out_v fp32 + vt_bf [h][d][n].
__global__ __launch_bounds__(256) void gemm_qkv_fused(const unsigned short* __restrict__ A,
                                                      const unsigned short* __restrict__ Bt,
                                                      float* __restrict__ out_k,
                                                      float* __restrict__ out_v,
                                                      unsigned short* __restrict__ q_bf,
                                                      unsigned short* __restrict__ k_bf,
                                                      unsigned short* __restrict__ vt_bf) {
    const int K = D_MODEL, N = QKV_COLS;
    __shared__ unsigned short As[128 * 32];
    __shared__ unsigned short Bs[128 * 32];
    int t = threadIdx.x;
    int w = t >> 6, lane = t & 63;
    int l16 = lane & 15, quad = lane >> 4;
    int wr = w >> 1, wc = w & 1;
    int by = blockIdx.y;
    int m0 = blockIdx.x * 128, n0 = by * 128;
    int srow = lane >> 2, scol = (lane & 3) * 8;
    int c0 = w * 2, c1 = c0 + 1;

    f32x4 acc[4][4] = {};

    for (int k0 = 0; k0 < K; k0 += 32) {
        __syncthreads();
        load_lds16(A  + (size_t)(m0 + c0 * 16 + srow) * K + k0 + scol, &As[c0 * 512 + lane * 8]);
        load_lds16(A  + (size_t)(m0 + c1 * 16 + srow) * K + k0 + scol, &As[c1 * 512 + lane * 8]);
        load_lds16(Bt + (size_t)(n0 + c0 * 16 + srow) * K + k0 + scol, &Bs[c0 * 512 + lane * 8]);
        load_lds16(Bt + (size_t)(n0 + c1 * 16 + srow) * K + k0 + scol, &Bs[c1 * 512 + lane * 8]);
        __syncthreads();
        bf16x8 a[4], b[4];
#pragma unroll
        for (int mt = 0; mt < 4; mt++)
            a[mt] = *(const bf16x8*)&As[(wr * 64 + mt * 16 + l16) * 32 + quad * 8];
#pragma unroll
        for (int nt = 0; nt < 4; nt++)
            b[nt] = *(const bf16x8*)&Bs[(wc * 64 + nt * 16 + l16) * 32 + quad * 8];
#pragma unroll
        for (int mt = 0; mt < 4; mt++)
#pragma unroll
            for (int nt = 0; nt < 4; nt++)
                acc[mt][nt] = MFMA32(a[mt], b[nt], acc[mt][nt]);
    }

    int typ = by >> 3;                 // 0=q 1=k 2=v (uniform per block)
    int hh  = (by & 7) * 2 + wc;       // head
    int nbase = m0 + wr * 64;

    if (typ == 0) {
        // q: scale by QSCALE, bf16 [h][n][d] (rope applied later in flash)
#pragma unroll
        for (int mt = 0; mt < 4; mt++)
#pragma unroll
            for (int nt = 0; nt < 4; nt++) {
                int d = nt * 16 + l16;
#pragma unroll
                for (int r = 0; r < 4; r++) {
                    int n = nbase + mt * 16 + quad * 4 + r;
                    q_bf[((size_t)hh * N_SEQ + n) * 64 + d] = f2bf(acc[mt][nt][r] * QSCALE);
                }
            }
    } else if (typ == 1) {
        // k: fp32 pre-rope cache + roped bf16
        float f_nt[4];
#pragma unroll
        for (int nt = 0; nt < 4; nt++)
            f_nt[nt] = exp2f((float)((nt * 16 + l16) >> 1) * -NLOG2TH);
#pragma unroll
        for (int mt = 0; mt < 4; mt++)
#pragma unroll
            for (int nt = 0; nt < 4; nt++) {
                int d = nt * 16 + l16;
#pragma unroll
                for (int r = 0; r < 4; r++) {
                    int n = nbase + mt * 16 + quad * 4 + r;
                    float x = acc[mt][nt][r];
                    out_k[((size_t)hh * N_SEQ + n) * 64 + d] = x;
                    float p = __shfl_xor(x, 1);
                    float sv, cv;
                    sincosf((float)n * f_nt[nt], &sv, &cv);
                    float ro = (d & 1) ? (x * cv + p * sv) : (x * cv - p * sv);
                    k_bf[((size_t)hh * N_SEQ + n) * 64 + d] = f2bf(ro);
                }
            }
    } else {
        // v: fp32 cache + transposed bf16 [h][d][n]
#pragma unroll
        for (int mt = 0; mt < 4; mt++)
#pragma unroll
            for (int nt = 0; nt < 4; nt++) {
                int d = nt * 16 + l16;
#pragma unroll
                for (int r = 0; r < 4; r++) {
                    int n = nbase + mt * 16 + quad * 4 + r;
                    out_v[((size_t)hh * N_SEQ + n) * 64 + d] = acc[mt][nt][r];
                }
                ushort4 o;
                o.x = f2bf(acc[mt][nt][0]);
                o.y = f2bf(acc[mt][nt][1]);
                o.z = f2bf(acc[mt][nt][2]);
                o.w = f2bf(acc[mt][nt][3]);
                *(ushort4*)&vt_bf[((size_t)hh * DHEAD + d) * N_SEQ + nbase + mt * 16 + quad * 4] = o;
            }
    }
}

// ------------- MFMA flash attention (causal, S^T form, split-K) -------------
// Q is pre-scaled; rope applied to Q in-register at load (d-pairs adjacent in frag).
__global__ __launch_bounds__(256, 4) void flash_mfma(const unsigned short* __restrict__ q_bf,
                                                     const unsigned short* __restrict__ k_bf,
                                                     const unsigned short* __restrict__ vt_bf,
                                                     unsigned short* __restrict__ attn_bf,
                                                     unsigned short* __restrict__ part_O,
                                                     float* __restrict__ part_l) {
    int idx = blockIdx.x;
    int h = idx & 15;
    int u = idx >> 4;                  // 0..79, heavy-first
    int Qt, cc;
    bool partial = (u < 72);
    if (partial) {
        int r = 71 - u;
        if (r < 16)      { Qt = 8 + (r >> 1); cc = r & 1; }
        else if (r < 40) { int q3 = r - 16; int d3 = q3 / 3; Qt = 16 + d3; cc = q3 - 3 * d3; }
        else             { int q4 = r - 40; Qt = 24 + (q4 >> 2); cc = q4 & 3; }
    } else { Qt = 79 - u; cc = 0; }
    int kt0 = cc * 16;
    int kt_end = min(kt0 + 15, 2 * Qt + 1);

    int t = threadIdx.x;
    int w = t >> 6, lane = t & 63;
    int l16 = lane & 15, quad = lane >> 4;
    int sw = l16 & 7;

    __shared__ unsigned short Ks[64 * 64];
    __shared__ unsigned short Vs[64 * 64];

    int qr0 = Qt * 128 + w * 32;
    const unsigned short* Kg = k_bf + (size_t)h * N_SEQ * DHEAD;
    const unsigned short* Vg = vt_bf + (size_t)h * DHEAD * N_SEQ;

    // load Q (pre-scaled) and rope in-register: pairs (2m,2m+1) are adjacent in frag
    bf16x8 bq[2][2];
#pragma unroll
    for (int qg = 0; qg < 2; qg++) {
        float nf = (float)(qr0 + qg * 16 + l16);
        const unsigned short* qp = q_bf + ((size_t)h * N_SEQ + qr0 + qg * 16 + l16) * 64 + quad * 8;
#pragma unroll
        for (int c = 0; c < 2; c++) {
            bf16x8 raw = *(const bf16x8*)(qp + c * 32);
            union { unsigned u[4]; bf16x8 v; } pk;
#pragma unroll
            for (int m = 0; m < 4; m++) {
                float x0 = bf2f((unsigned short)raw[2 * m]);
                float x1 = bf2f((unsigned short)raw[2 * m + 1]);
                float fi = exp2f((float)(quad * 4 + c * 16 + m) * -NLOG2TH);
                float sv, cv;
                sincosf(nf * fi, &sv, &cv);
                pk.u[m] = packbf2(x0 * cv - x1 * sv, x1 * cv + x0 * sv);
            }
            bq[qg][c] = pk.v;
        }
    }
    f32x4 O[2][4] = {};
    float lp[2] = {0.f, 0.f};
    int my_kmax = (qr0 + 31) >> 6;

    int srow = t >> 3;
    int scol = ((t & 7) ^ (srow & 7)) * 8;

    for (int kt = kt0; kt <= kt_end; kt++) {
        int k0 = kt << 6;
        __syncthreads();
        load_lds16(Kg + (size_t)(k0 + srow) * 64 + scol,         &Ks[t * 8]);
        load_lds16(Kg + (size_t)(k0 + srow + 32) * 64 + scol,    &Ks[t * 8 + 2048]);
        load_lds16(Vg + (size_t)srow * N_SEQ + k0 + scol,        &Vs[t * 8]);
        load_lds16(Vg + (size_t)(srow + 32) * N_SEQ + k0 + scol, &Vs[t * 8 + 2048]);
        __syncthreads();
        if (kt > my_kmax) continue;

        bf16x4 pf[2][4];
#pragma unroll
        for (int tt = 0; tt < 4; tt++) {
            int kbase = k0 + tt * 16;
            bf16x4 pz = (bf16x4){0, 0, 0, 0};
            if (kbase >= qr0 + 32) { pf[0][tt] = pz; pf[1][tt] = pz; continue; }
            int krow = tt * 16 + l16;
            bf16x8 kf0 = *(const bf16x8*)&Ks[krow * 64 + ((quad ^ sw) * 8)];
            bf16x8 kf1 = *(const bf16x8*)&Ks[krow * 64 + (((quad + 4) ^ sw) * 8)];
#pragma unroll
            for (int qg = 0; qg < 2; qg++) {
                int qb = qr0 + qg * 16;
                if (kbase > qb) { pf[qg][tt] = pz; continue; }
                f32x4 s = (f32x4){0.f, 0.f, 0.f, 0.f};
                s = MFMA32(kf0, bq[qg][0], s);
                s = MFMA32(kf1, bq[qg][1], s);
                float p0 = exp2f(s[0]);
                float p1 = exp2f(s[1]);
                float p2 = exp2f(s[2]);
                float p3 = exp2f(s[3]);
                if (kbase == qb) {
                    if (quad * 4 + 0 > l16) p0 = 0.f;
                    if (quad * 4 + 1 > l16) p1 = 0.f;
                    if (quad * 4 + 2 > l16) p2 = 0.f;
                    if (quad * 4 + 3 > l16) p3 = 0.f;
                }
                lp[qg] += (p0 + p1) + (p2 + p3);
                pf[qg][tt] = pack_bf16x4(p0, p1, p2, p3);
            }
        }
#pragma unroll
        for (int tt = 0; tt < 4; tt++) {
            if (k0 + tt * 16 < qr0 + 32) {
#pragma unroll
                for (int dt = 0; dt < 4; dt++) {
                    int vrow = dt * 16 + l16;
                    bf16x4 va = *(const bf16x4*)&Vs[vrow * 64 +
                                (((2 * tt + (quad >> 1)) ^ sw) * 8) + (quad & 1) * 4];
                    O[0][dt] = MFMA16(va, pf[0][tt], O[0][dt]);
                    O[1][dt] = MFMA16(va, pf[1][tt], O[1][dt]);
                }
            }
        }
    }

#pragma unroll
    for (int qg = 0; qg < 2; qg++) {
        float l = lp[qg];
        l += __shfl_xor(l, 16);
        l += __shfl_xor(l, 32);
        if (!partial) {
            float inv = 1.0f / l;
#pragma unroll
            for (int dt = 0; dt < 4; dt++) {
                ushort4 o;
                o.x = f2bf(O[qg][dt][0] * inv);
                o.y = f2bf(O[qg][dt][1] * inv);
                o.z = f2bf(O[qg][dt][2] * inv);
                o.w = f2bf(O[qg][dt][3] * inv);
                *(ushort4*)(attn_bf + (size_t)(qr0 + qg * 16 + l16) * D_MODEL + h * 64 + dt * 16 + quad * 4) = o;
            }
        } else {
            int uid = h * 72 + u;
            size_t ob = (size_t)uid * 8192;
            int qcol = w * 32 + qg * 16 + l16;
#pragma unroll
            for (int dt = 0; dt < 4; dt++)
#pragma unroll
                for (int r = 0; r < 4; r++)
                    part_O[ob + (size_t)(dt * 16 + quad * 4 + r) * 128 + qcol] = f2bf(O[qg][dt][r]);
            if (quad == 0) part_l[uid * 128 + qcol] = l;
        }
    }
}

// ------------- combine partials: sum chunks, normalize, -> attn_bf -------------
__global__ __launch_bounds__(256) void combine_kernel(const unsigned short* __restrict__ part_O,
                                                      const float* __restrict__ part_l,
                                                      unsigned short* __restrict__ attn_bf) {
    int Qt = 8 + blockIdx.x;       // 8..31
    int h  = blockIdx.y;
    int nc = (Qt + 8) >> 3;        // 2,3,4 chunks
    int t = threadIdx.x;
    int q = t & 127;
    int dh = (t >> 7) * 32;
    float l = 0.f;
    float acc[32];
#pragma unroll
    for (int d = 0; d < 32; d++) acc[d] = 0.f;
    for (int c = 0; c < nc; c++) {
        int r;
        if (Qt < 16)      r = 2 * (Qt - 8) + c;
        else if (Qt < 24) r = 16 + 3 * (Qt - 16) + c;
        else              r = 40 + 4 * (Qt - 24) + c;
        int uid = h * 72 + (71 - r);
        l += part_l[uid * 128 + q];
        const unsigned short* po = part_O + (size_t)uid * 8192 + (size_t)dh * 128 + q;
#pragma unroll
        for (int d = 0; d < 32; d++) acc[d] += bf2f(po[d * 128]);
    }
    float inv = 1.0f / l;
    unsigned short* op = attn_bf + (size_t)(Qt * 128 + q) * D_MODEL + h * 64 + dh;
#pragma unroll
    for (int d = 0; d < 32; d++) op[d] = f2bf(acc[d] * inv);
}

extern "C" void kernel_launch(void* const* d_in, const int* in_sizes, int n_in,
                              void* d_out, int out_size, void* d_ws, size_t ws_size,
                              hipStream_t stream) {
    const float* x     = (const float*)d_in[0];
    const float* w_qkv = (const float*)d_in[1];
    const float* w_out = (const float*)d_in[2];
    const float* ln_g  = (const float*)d_in[3];
    const float* ln_b  = (const float*)d_in[4];

    float* out   = (float*)d_out;                       // [4096,1024]
    float* out_k = (float*)d_out + 4194304;             // [16,4096,64]
    float* out_v = (float*)d_out + 8388608;             // [16,4096,64]

    char* ws = (char*)d_ws;
    const size_t MiB = 1048576;
    unsigned short* q_bf    = (unsigned short*)(ws);           // [16,4096,64] bf16  @0..8
    unsigned short* k_bf    = (unsigned short*)(ws + 8*MiB);   // [16,4096,64] bf16  @8..16
    unsigned short* vt_bf   = (unsigned short*)(ws + 16*MiB);  // [16,64,4096] bf16  @16..24
    unsigned short* attn_bf = (unsigned short*)(ws + 24*MiB);  // [4096,1024] bf16   @24..32
    float*          part_l  = (float*)(ws + 32*MiB);           // [1152][128] fp32   @32..33
    unsigned short* part_O  = (unsigned short*)(ws + 33*MiB);  // [1152][64][128] bf16 @33..51
    unsigned short* h_bf    = (unsigned short*)(ws + 52*MiB);  // [4096,1024] bf16   @52..60
    unsigned short* wqkvT   = (unsigned short*)(ws + 60*MiB);  // [3072,1024] bf16   @60..66
    unsigned short* woutT   = (unsigned short*)(ws + 66*MiB);  // [1024,1024] bf16   @66..68

    transpose_cvt<<<dim3(16, 48), 256, 0, stream>>>(w_qkv, wqkvT, D_MODEL, QKV_COLS);
    transpose_cvt<<<dim3(16, 16), 256, 0, stream>>>(w_out, woutT, D_MODEL, D_MODEL);
    ln_kernel<<<N_SEQ, 256, 0, stream>>>(x, ln_g, ln_b, h_bf);
    gemm_qkv_fused<<<dim3(32, 24), 256, 0, stream>>>(h_bf, wqkvT, out_k, out_v, q_bf, k_bf, vt_bf);
    flash_mfma<<<1280, 256, 0, stream>>>(q_bf, k_bf, vt_bf, attn_bf, part_O, part_l);
    combine_kernel<<<dim3(24, 16), 256, 0, stream>>>(part_O, part_l, attn_bf);
    gemm_bt128<<<dim3(32, 8), 256, 0, stream>>>(attn_bf, woutT, out, N_SEQ, D_MODEL, D_MODEL);
}